// Round 9
// baseline (2918.863 us; speedup 1.0000x reference)
//
#include <hip/hip_runtime.h>
#include <hip/hip_bf16.h>
#include <cstddef>
#include <cstdint>

#define NS   16384
#define HS   512
#define DS   128
#define KOBS 40
#define ES   4096
#define DTC  0.05f

typedef __bf16 bf16x8 __attribute__((ext_vector_type(8)));
typedef float  f32x4  __attribute__((ext_vector_type(4)));
typedef __hip_bfloat16 bf16_t;

__device__ __forceinline__ void async16(const void* g, void* l)
{
  __builtin_amdgcn_global_load_lds(
      (const __attribute__((address_space(1))) unsigned int*)g,
      (__attribute__((address_space(3))) unsigned int*)l, 16, 0, 0);
}

// fast tanh: 1 - 2/(1+e^{2x}); |err| ~1e-7 rel, far below bf16 quantization.
__device__ __forceinline__ float fast_tanh(float x)
{
  return 1.f - 2.f / (1.f + __expf(2.f * x));
}

// ---------------------------------------------------------------------------
// One BK=32 half-step from [rows][32] LDS tiles (64B row stride).
// A-frag: lane holds A[m=ln][k=q*8+0..7]; C/D: col=ln, row=q*4+r.
// ---------------------------------------------------------------------------
template <int IT, int JT>
__device__ __forceinline__ void mfma_half(
    f32x4 (&acc)[IT][JT], const bf16_t* Ah, const bf16_t* Bh,
    int wr, int wc, int q, int ln)
{
  bf16x8 a[IT], b[JT];
#pragma unroll
  for (int i = 0; i < IT; ++i)
    a[i] = *(const bf16x8*)(Ah + (wr + i * 16 + ln) * 32 + q * 8);
#pragma unroll
  for (int j = 0; j < JT; ++j)
    b[j] = *(const bf16x8*)(Bh + (wc + j * 16 + ln) * 32 + q * 8);
#pragma unroll
  for (int i = 0; i < IT; ++i)
#pragma unroll
    for (int j = 0; j < JT; ++j)
      acc[i][j] = __builtin_amdgcn_mfma_f32_16x16x32_bf16(a[i], b[j], acc[i][j], 0, 0, 0);
}

// ---------------------------------------------------------------------------
// k_obs_pre K-loop: 128x64 block tile, BK=128, 256 threads (4 waves, 2x2).
// As = 4 x [128][32] (32 KB), Bs = 4 x [64][32] (16 KB) -> 48 KB LDS
// -> 2 blocks/CU (verified round 7: obs path ~10 us/iter, was ~26).
// ---------------------------------------------------------------------------
__device__ __forceinline__ void loop_pre(
    f32x4 (&acc)[4][2],
    const bf16_t* __restrict__ A, const int* __restrict__ idx, int row0,
    const bf16_t* __restrict__ W, int ldw, int col0, int K,
    bf16_t* As, bf16_t* Bs)
{
  const int tid = threadIdx.x, wave = tid >> 6, lane = tid & 63;
  const int q = lane >> 4, ln = lane & 15;
  const int wr = (wave >> 1) * 64, wc = (wave & 1) * 32;
  const int srow = wave * 16 + (lane >> 2);   // 0..63
  const int skc  = (lane & 3) * 8;
  int ar0 = row0 + srow, ar1 = row0 + srow + 64;
  if (idx) { ar0 = idx[ar0]; ar1 = idx[ar1]; }
  const bf16_t* Ap0 = A + (size_t)ar0 * HS + skc;
  const bf16_t* Ap1 = A + (size_t)ar1 * HS + skc;
  const int brow = tid >> 2;                  // 0..63
  const bf16_t* Bp = W + (size_t)(col0 + brow) * ldw + skc;
  const int d0 = srow * 32 + skc, d1 = (srow + 64) * 32 + skc;
  const int db = brow * 32 + skc;

  for (int k0 = 0; k0 < K; k0 += 128) {
    __syncthreads();
#pragma unroll
    for (int s = 0; s < 4; ++s) {
      async16(Ap0 + k0 + s * 32, As + s * 4096 + d0);
      async16(Ap1 + k0 + s * 32, As + s * 4096 + d1);
      async16(Bp  + k0 + s * 32, Bs + s * 2048 + db);
    }
    __syncthreads();
#pragma unroll
    for (int s = 0; s < 4; ++s)
      mfma_half<4, 2>(acc, As + s * 4096, Bs + s * 2048, wr, wc, q, ln);
  }
}

// ---------------------------------------------------------------------------
// k_obs_post loss K-loop: 64x32 block tile, BK=64, 256 threads (4 waves 2x2).
// As = 2 x [64][32] (8 KB), Bs = 2 x [32][32] (4 KB).
// ---------------------------------------------------------------------------
__device__ __forceinline__ void loop_post(
    f32x4 (&acc)[2][1],
    const bf16_t* __restrict__ A, int row0,
    const bf16_t* __restrict__ W, int col0, int K,
    bf16_t* As, bf16_t* Bs)
{
  const int tid = threadIdx.x, wave = tid >> 6, lane = tid & 63;
  const int q = lane >> 4, ln = lane & 15;
  const int wr = (wave >> 1) * 32, wc = (wave & 1) * 16;
  const int srow = tid >> 2;                  // 0..63
  const int skc  = (tid & 3) * 8;
  const bf16_t* Ap = A + (size_t)(row0 + srow) * HS + skc;
  const int d = srow * 32 + skc;
  const int brow = (tid & 127) >> 2;          // 0..31 (tid<128 stages B)
  const bf16_t* Bp = W + (size_t)(col0 + brow) * HS + skc;
  const int dbB = brow * 32 + skc;

  for (int k0 = 0; k0 < K; k0 += 64) {
    __syncthreads();
    async16(Ap + k0,      As + d);
    async16(Ap + k0 + 32, As + 2048 + d);
    if (tid < 128) {                          // waves 0,1 fully active
      async16(Bp + k0,      Bs + dbB);
      async16(Bp + k0 + 32, Bs + 1024 + dbB);
    }
    __syncthreads();
    mfma_half<2, 1>(acc, As,        Bs,        wr, wc, q, ln);
    mfma_half<2, 1>(acc, As + 2048, Bs + 1024, wr, wc, q, ln);
  }
}

// ---------------------------------------------------------------------------
// Fused double-Euler kernel, 1024 threads (16 waves = 4 waves/SIMD).
//
// Hs/Ts [64][512] bf16, XOR-swizzled: elem (row,col) at byte
//   row*1024 + ((((col*2)>>4) ^ (row&7))<<4) + ((col*2)&15).
// Operand-swapped MFMA: acc[i][jb] = mfma(Wfrag[i], Hfrag[jb], acc);
// each lane gets ONE h-row and 4 consecutive cols -> b64 epilogue LDS ops.
// W frag-major (k_cvt_frag).
//
// FULL double-sided ping-pong (W from L2 + T from LDS, 1 slice ahead):
// at 16 waves per-wave live set = acc 32 + wA/wB 16 + tA/tB 32 + addr
// ~= 105 < the 128-VGPR cap of 4 waves/SIMD.  (Round 5 showed the same
// pattern spills at 8 waves where acc=64; round 8 showed just-in-time
// t-loads leave ~2x serialization vs the ~21 us pipe floor.)
// s_setprio NOT used: measured -20% on this kernel (round 7).
// Spill tripwire: WRITE_SIZE must stay 16384 KB.
// ---------------------------------------------------------------------------
__device__ __forceinline__ void gemm_k512(
    f32x4 (&acc)[2][4], const char* Tb, const bf16_t* __restrict__ Wf,
    int wc, int q, int ln)
{
  const int abase = ln * 1024;
  const int l3 = ln & 7;
  const bf16_t* Wl = Wf + (q * 512 + wc + ln) * 8;   // frag-major base
  bf16x8 wA[2], wB[2], tA[4], tB[4];
  // preload slice 0
#pragma unroll
  for (int i = 0; i < 2; ++i) wA[i] = *(const bf16x8*)(Wl + i * 128);
  {
    const int c0 = (q ^ l3) << 4;
#pragma unroll
    for (int jb = 0; jb < 4; ++jb)
      tA[jb] = *(const bf16x8*)(Tb + jb * 16384 + abase + c0);
  }
#pragma unroll 1
  for (int ks2 = 0; ks2 < 8; ++ks2) {
    // prefetch slice 2k+1 -> B buffers; compute slice 2k from A buffers
    {
      const bf16_t* Wk = Wl + (2 * ks2 + 1) * 16384;
#pragma unroll
      for (int i = 0; i < 2; ++i) wB[i] = *(const bf16x8*)(Wk + i * 128);
      const int c1 = (((2 * ks2 + 1) * 4 + q) ^ l3) << 4;
#pragma unroll
      for (int jb = 0; jb < 4; ++jb)
        tB[jb] = *(const bf16x8*)(Tb + jb * 16384 + abase + c1);
    }
#pragma unroll
    for (int i = 0; i < 2; ++i)
#pragma unroll
      for (int jb = 0; jb < 4; ++jb)
        acc[i][jb] = __builtin_amdgcn_mfma_f32_16x16x32_bf16(wA[i], tA[jb], acc[i][jb], 0, 0, 0);
    // prefetch slice 2k+2 -> A buffers (guarded); compute 2k+1 from B
    if (ks2 < 7) {
      const bf16_t* Wk = Wl + (2 * ks2 + 2) * 16384;
#pragma unroll
      for (int i = 0; i < 2; ++i) wA[i] = *(const bf16x8*)(Wk + i * 128);
      const int c2 = (((2 * ks2 + 2) * 4 + q) ^ l3) << 4;
#pragma unroll
      for (int jb = 0; jb < 4; ++jb)
        tA[jb] = *(const bf16x8*)(Tb + jb * 16384 + abase + c2);
    }
#pragma unroll
    for (int i = 0; i < 2; ++i)
#pragma unroll
      for (int jb = 0; jb < 4; ++jb)
        acc[i][jb] = __builtin_amdgcn_mfma_f32_16x16x32_bf16(wB[i], tB[jb], acc[i][jb], 0, 0, 0);
  }
}

__global__ __launch_bounds__(1024) void k_euler2(
    bf16_t* __restrict__ h,
    const bf16_t* __restrict__ Wo1, const float* __restrict__ bo1,
    const bf16_t* __restrict__ Wo2, const float* __restrict__ bo2)
{
  __shared__ __align__(16) char Hs[64 * 1024];
  __shared__ __align__(16) char Ts[64 * 1024];
  const int tid = threadIdx.x;
  const int wave = tid >> 6, lane = tid & 63;
  const int q = lane >> 4, ln = lane & 15;
  const int wc = wave * 32;                   // 16 waves x 32-col stripes
  const int r0 = blockIdx.x * 64;

  // stage h -> Hs (swizzled): 4096 16B chunks, 4 per thread, coalesced.
#pragma unroll
  for (int u = 0; u < 4; ++u) {
    const int g = u * 1024 + tid;
    const int row = g >> 6, c16 = g & 63;
    *(uint4*)(Hs + row * 1024 + ((c16 ^ (row & 7)) << 4)) =
        *(const uint4*)(h + (size_t)(r0 + row) * HS + c16 * 8);
  }
  __syncthreads();

#pragma unroll 1
  for (int step = 0; step < 2; ++step) {
    // T = tanh(h @ Wo1^T + bo1)
    {
      f32x4 acc[2][4] = {};
      gemm_k512(acc, Hs, Wo1, wc, q, ln);
#pragma unroll
      for (int i = 0; i < 2; ++i) {
        const int c0 = wc + i * 16 + q * 4;
        const float4 b4 = *(const float4*)(bo1 + c0);
        const int cb = c0 * 2;
#pragma unroll
        for (int jb = 0; jb < 4; ++jb) {
          const int row = jb * 16 + ln;
          __attribute__((aligned(8))) bf16_t pk[4];
          pk[0] = __float2bfloat16(fast_tanh(acc[i][jb][0] + b4.x));
          pk[1] = __float2bfloat16(fast_tanh(acc[i][jb][1] + b4.y));
          pk[2] = __float2bfloat16(fast_tanh(acc[i][jb][2] + b4.z));
          pk[3] = __float2bfloat16(fast_tanh(acc[i][jb][3] + b4.w));
          *(uint2*)(Ts + row * 1024 + (((cb >> 4) ^ (row & 7)) << 4) + (cb & 15)) =
              *(const uint2*)pk;
        }
      }
    }
    __syncthreads();   // Ts complete (and all Hs reads of this step done)
    // h = h + DT * (T @ Wo2^T + bo2)
    {
      f32x4 acc[2][4] = {};
      gemm_k512(acc, Ts, Wo2, wc, q, ln);
#pragma unroll
      for (int i = 0; i < 2; ++i) {
        const int c0 = wc + i * 16 + q * 4;
        const float4 b4 = *(const float4*)(bo2 + c0);
        const int cb = c0 * 2;
#pragma unroll
        for (int jb = 0; jb < 4; ++jb) {
          const int row = jb * 16 + ln;
          char* p = Hs + row * 1024 + (((cb >> 4) ^ (row & 7)) << 4) + (cb & 15);
          uint2 ov = *(const uint2*)p;
          const bf16_t* ob = (const bf16_t*)&ov;
          __attribute__((aligned(8))) bf16_t pk[4];
          pk[0] = __float2bfloat16(__bfloat162float(ob[0]) + DTC * (acc[i][jb][0] + b4.x));
          pk[1] = __float2bfloat16(__bfloat162float(ob[1]) + DTC * (acc[i][jb][1] + b4.y));
          pk[2] = __float2bfloat16(__bfloat162float(ob[2]) + DTC * (acc[i][jb][2] + b4.z));
          pk[3] = __float2bfloat16(__bfloat162float(ob[3]) + DTC * (acc[i][jb][3] + b4.w));
          *(uint2*)p = *(const uint2*)pk;
        }
      }
    }
    __syncthreads();   // Hs updated; safe for next step's GEMM1 / final store
  }

  // store Hs -> h
#pragma unroll
  for (int u = 0; u < 4; ++u) {
    const int g = u * 1024 + tid;
    const int row = g >> 6, c16 = g & 63;
    *(uint4*)(h + (size_t)(r0 + row) * HS + c16 * 8) =
        *(const uint4*)(Hs + row * 1024 + ((c16 ^ (row & 7)) << 4));
  }
}

// ---------------------------------------------------------------------------
// Fused: z==0 -> tmpE = relu(h[idx] @ Wp1^T + bp1)
//        z==1 -> hnewE = tanh(Xk @ Wih^T + b_ih + h[idx] @ Whh^T + b_hh)
// Grid (32, 8, 2) = 512 blocks of (128 rows x 64 cols), 48 KB LDS
// -> 2 blocks/CU for latency overlap.  (verified round 7)
__global__ __launch_bounds__(256) void k_obs_pre(
    const bf16_t* __restrict__ h, const int* __restrict__ idx,
    const bf16_t* __restrict__ Wp1, const float* __restrict__ bp1,
    bf16_t* __restrict__ tmpE,
    const float* __restrict__ Xk,
    const bf16_t* __restrict__ Wih, const float* __restrict__ b_ih,
    const bf16_t* __restrict__ Whh, const float* __restrict__ b_hh,
    bf16_t* __restrict__ hnewE)
{
  __shared__ bf16_t As[128 * 128], Bs[64 * 128];
  f32x4 acc[4][2] = {};
  const int tid = threadIdx.x, wave = tid >> 6, lane = tid & 63;
  const int q = lane >> 4, ln = lane & 15;
  const int wr = (wave >> 1) * 64, wc = (wave & 1) * 32;
  const int row0 = blockIdx.x * 128, col0 = blockIdx.y * 64;

  if (blockIdx.z == 0) {
    loop_pre(acc, h, idx, row0, Wp1, HS, col0, HS, As, Bs);
#pragma unroll
    for (int j = 0; j < 2; ++j) {
      const int c = col0 + wc + j * 16 + ln;
      const float bj = bp1[c];
#pragma unroll
      for (int i = 0; i < 4; ++i)
#pragma unroll
        for (int r = 0; r < 4; ++r) {
          const int rw = row0 + wr + i * 16 + q * 4 + r;
          const float v = acc[i][j][r] + bj;
          tmpE[(size_t)rw * HS + c] = __float2bfloat16(v > 0.f ? v : 0.f);
        }
    }
  } else {
    // phase 1: Xk (fp32) @ Wih^T, K = DS = 128, single BK=128 barrier pair
    {
      const int brow = tid >> 2;
      const int skc  = (tid & 3) * 8;
      const bf16_t* Bp = Wih + (size_t)(col0 + brow) * DS + skc;
      const int db = brow * 32 + skc;
      const int xr = tid >> 1, xh = (tid & 1) * 16;
#pragma unroll
      for (int s = 0; s < 4; ++s)
        async16(Bp + s * 32, Bs + s * 2048 + db);
#pragma unroll
      for (int s = 0; s < 4; ++s) {
        const float* src = Xk + (size_t)(row0 + xr) * DS + s * 32 + xh;
        __attribute__((aligned(16))) bf16_t buf[16];
#pragma unroll
        for (int u = 0; u < 16; ++u) buf[u] = __float2bfloat16(src[u]);
        *(uint4*)(As + s * 4096 + xr * 32 + xh)     = *(const uint4*)buf;
        *(uint4*)(As + s * 4096 + xr * 32 + xh + 8) = *(const uint4*)(buf + 8);
      }
      __syncthreads();
#pragma unroll
      for (int s = 0; s < 4; ++s)
        mfma_half<4, 2>(acc, As + s * 4096, Bs + s * 2048, wr, wc, q, ln);
    }
    // phase 2: h[idx] @ Whh^T, K = HS (loop_pre's leading barrier protects As)
    loop_pre(acc, h, idx, row0, Whh, HS, col0, HS, As, Bs);
#pragma unroll
    for (int j = 0; j < 2; ++j) {
      const int c = col0 + wc + j * 16 + ln;
      const float bj = b_ih[c] + b_hh[c];
#pragma unroll
      for (int i = 0; i < 4; ++i)
#pragma unroll
        for (int r = 0; r < 4; ++r) {
          const int rw = row0 + wr + i * 16 + q * 4 + r;
          hnewE[(size_t)rw * HS + c] = __float2bfloat16(fast_tanh(acc[i][j][r] + bj));
        }
    }
  }
}

// Fused: blocks [0,256) -> loss GEMM (64x32 tiles, full GPU);
//        [256,1280) -> scatter
__global__ __launch_bounds__(256) void k_obs_post(
    const bf16_t* __restrict__ tmpE, const bf16_t* __restrict__ Wp2,
    const float* __restrict__ bp2, const float* __restrict__ X,
    const float* __restrict__ Mm, float* __restrict__ accum,
    bf16_t* __restrict__ h, const bf16_t* __restrict__ hnewE,
    const int* __restrict__ idx)
{
  const int bid = blockIdx.x;
  if (bid >= 256) {
    const int t  = (bid - 256) * 256 + threadIdx.x;
    const int r  = t >> 6;
    const int c8 = (t & 63) * 8;
    const int gr = idx[r];
    *(uint4*)(h + (size_t)gr * HS + c8) = *(const uint4*)(hnewE + (size_t)r * HS + c8);
    return;
  }
  __shared__ bf16_t As[64 * 64], Bs[32 * 64];
  f32x4 acc[2][1] = {};
  const int wave = threadIdx.x >> 6, lane = threadIdx.x & 63;
  const int q = lane >> 4, ln = lane & 15;
  const int wr = (wave >> 1) * 32, wc = (wave & 1) * 16;
  const int row0 = (bid >> 2) * 64, col0 = (bid & 3) * 32;
  loop_post(acc, tmpE, row0, Wp2, col0, HS, As, Bs);
  float ls = 0.f;
  {
    const int c = col0 + wc + ln;
    const float bj = bp2[c];
#pragma unroll
    for (int i = 0; i < 2; ++i)
#pragma unroll
      for (int r = 0; r < 4; ++r) {
        const int rw = row0 + wr + i * 16 + q * 4 + r;
        const float p = acc[i][0][r] + bj;
        const size_t o = (size_t)rw * DS + c;
        ls += fabsf(X[o] - p) * Mm[o];
      }
  }
#pragma unroll
  for (int off = 32; off > 0; off >>= 1) ls += __shfl_down(ls, off);
  __shared__ float red[4];
  if (lane == 0) red[wave] = ls;
  __syncthreads();
  if (threadIdx.x == 0) atomicAdd(accum, red[0] + red[1] + red[2] + red[3]);
}

__global__ void k_cvt(const float* __restrict__ s, bf16_t* __restrict__ d, int n)
{
  const int i = blockIdx.x * 256 + threadIdx.x;
  if (i * 4 < n) {
    const float4 v = ((const float4*)s)[i];
    d[i * 4 + 0] = __float2bfloat16(v.x);
    d[i * 4 + 1] = __float2bfloat16(v.y);
    d[i * 4 + 2] = __float2bfloat16(v.z);
    d[i * 4 + 3] = __float2bfloat16(v.w);
  }
}

// fp32 [512][512] row-major -> frag-major bf16: chunk (c,r) at elems
// (c*512 + r)*8 holds W[r][c*8 .. c*8+8).  t = c*512 + r, coalesced stores.
__global__ void k_cvt_frag(const float* __restrict__ s, bf16_t* __restrict__ d)
{
  const int t = blockIdx.x * 256 + threadIdx.x;
  const int r = t & 511, c = t >> 9;
  const float4 v0 = *(const float4*)(s + (size_t)r * HS + c * 8);
  const float4 v1 = *(const float4*)(s + (size_t)r * HS + c * 8 + 4);
  __attribute__((aligned(16))) bf16_t buf[8];
  buf[0] = __float2bfloat16(v0.x); buf[1] = __float2bfloat16(v0.y);
  buf[2] = __float2bfloat16(v0.z); buf[3] = __float2bfloat16(v0.w);
  buf[4] = __float2bfloat16(v1.x); buf[5] = __float2bfloat16(v1.y);
  buf[6] = __float2bfloat16(v1.z); buf[7] = __float2bfloat16(v1.w);
  *(uint4*)(d + (size_t)t * 8) = *(const uint4*)buf;
}

__global__ void k_zero(float* __restrict__ p, size_t n4)
{
  size_t i = (size_t)blockIdx.x * blockDim.x + threadIdx.x;
  const size_t st = (size_t)gridDim.x * blockDim.x;
  const float4 z = {0.f, 0.f, 0.f, 0.f};
  for (; i < n4; i += st) ((float4*)p)[i] = z;
}

__global__ void k_zero_accum(float* accum)
{
  if (threadIdx.x < 2) accum[threadIdx.x] = 0.f;
}

__global__ void k_sum(const float* __restrict__ M, size_t n4, float* __restrict__ accum)
{
  __shared__ float red[256];
  float s = 0.f;
  for (size_t i = (size_t)blockIdx.x * blockDim.x + threadIdx.x; i < n4;
       i += (size_t)gridDim.x * blockDim.x) {
    const float4 v = ((const float4*)M)[i];
    s += v.x + v.y + v.z + v.w;
  }
  red[threadIdx.x] = s;
  __syncthreads();
  for (int st = 128; st > 0; st >>= 1) {
    if (threadIdx.x < st) red[threadIdx.x] += red[threadIdx.x + st];
    __syncthreads();
  }
  if (threadIdx.x == 0) atomicAdd(accum + 1, red[0]);
}

__global__ void k_final(const float* __restrict__ accum, float* __restrict__ out)
{
  out[0] = accum[0];
  out[1] = accum[0] / accum[1];
}

// ---------------------------------------------------------------------------
extern "C" void kernel_launch(void* const* d_in, const int* in_sizes, int n_in,
                              void* d_out, int out_size, void* d_ws, size_t ws_size,
                              hipStream_t stream)
{
  const float* X    = (const float*)d_in[0];
  const float* M    = (const float*)d_in[1];
  const int*   bidx = (const int*)d_in[2];
  const float* W_ih = (const float*)d_in[3];
  const float* b_ih = (const float*)d_in[4];
  const float* W_hh = (const float*)d_in[5];
  const float* b_hh = (const float*)d_in[6];
  const float* Wo1  = (const float*)d_in[7];
  const float* bo1  = (const float*)d_in[8];
  const float* Wo2  = (const float*)d_in[9];
  const float* bo2  = (const float*)d_in[10];
  const float* Wp1  = (const float*)d_in[11];
  const float* bp1  = (const float*)d_in[12];
  const float* Wp2  = (const float*)d_in[13];
  const float* bp2  = (const float*)d_in[14];
  float* out = (float*)d_out;

  char* w = (char*)d_ws;
  bf16_t* h     = (bf16_t*)w;                         w += (size_t)NS * HS * 2;
  bf16_t* tmpE  = (bf16_t*)w;                         w += (size_t)ES * HS * 2;
  bf16_t* hnewE = (bf16_t*)w;                         w += (size_t)ES * HS * 2;
  bf16_t* wWo1  = (bf16_t*)w;                         w += (size_t)HS * HS * 2;
  bf16_t* wWo2  = (bf16_t*)w;                         w += (size_t)HS * HS * 2;
  bf16_t* wWp1  = (bf16_t*)w;                         w += (size_t)HS * HS * 2;
  bf16_t* wWp2  = (bf16_t*)w;                         w += (size_t)DS * HS * 2;
  bf16_t* wWih  = (bf16_t*)w;                         w += (size_t)HS * DS * 2;
  bf16_t* wWhh  = (bf16_t*)w;                         w += (size_t)HS * HS * 2;
  float*  accum = (float*)w;

  k_zero<<<2048, 256, 0, stream>>>((float*)h, (size_t)NS * HS * 2 / 16);
  k_zero_accum<<<1, 64, 0, stream>>>(accum);
  k_sum<<<2048, 256, 0, stream>>>(M, (size_t)KOBS * ES * DS / 4, accum);
  k_cvt_frag<<<128, 256, 0, stream>>>(Wo1, wWo1);   // frag-major for k_euler2
  k_cvt_frag<<<128, 256, 0, stream>>>(Wo2, wWo2);
  k_cvt<<<256, 256, 0, stream>>>(Wp1, wWp1, HS * HS);
  k_cvt<<<64, 256, 0, stream>>>(Wp2, wWp2, DS * HS);
  k_cvt<<<64, 256, 0, stream>>>(W_ih, wWih, HS * DS);
  k_cvt<<<256, 256, 0, stream>>>(W_hh, wWhh, HS * HS);

  const dim3 gPre(ES / 128, HS / 64, 2);       // 32 x 8 x 2 = 512 blocks
  const int  gPost = 256 + ES * HS / 8 / 256;  // 256 loss + 1024 scatter

  for (int k = 0; k < KOBS; ++k) {
    const int*   idx = bidx + (size_t)k * ES;
    const float* Xk  = X + (size_t)k * ES * DS;
    const float* Mk  = M + (size_t)k * ES * DS;

    // both Euler steps fused; h tile resident in LDS; 16 waves/CU
    k_euler2<<<NS / 64, 1024, 0, stream>>>(h, wWo1, bo1, wWo2, bo2);
    k_obs_pre <<<gPre, 256, 0, stream>>>(h, idx, wWp1, bp1, tmpE,
                                         Xk, wWih, b_ih, wWhh, b_hh, hnewE);
    k_obs_post<<<gPost, 256, 0, stream>>>(tmpE, wWp2, bp2, Xk, Mk, accum,
                                          h, hnewE, idx);
  }

  k_final<<<1, 1, 0, stream>>>(accum, out);
}

// Round 10
// 2841.470 us; speedup vs baseline: 1.0272x; 1.0272x over previous
//
#include <hip/hip_runtime.h>
#include <hip/hip_bf16.h>
#include <cstddef>
#include <cstdint>

#define NS   16384
#define HS   512
#define DS   128
#define KOBS 40
#define ES   4096
#define DTC  0.05f

typedef __bf16 bf16x8 __attribute__((ext_vector_type(8)));
typedef float  f32x4  __attribute__((ext_vector_type(4)));
typedef __hip_bfloat16 bf16_t;

__device__ __forceinline__ void async16(const void* g, void* l)
{
  __builtin_amdgcn_global_load_lds(
      (const __attribute__((address_space(1))) unsigned int*)g,
      (__attribute__((address_space(3))) unsigned int*)l, 16, 0, 0);
}

// fast tanh: 1 - 2/(1+e^{2x}); |err| ~1e-7 rel, far below bf16 quantization.
__device__ __forceinline__ float fast_tanh(float x)
{
  return 1.f - 2.f / (1.f + __expf(2.f * x));
}

// ---------------------------------------------------------------------------
// One BK=32 half-step from [rows][32] LDS tiles (64B row stride).
// A-frag: lane holds A[m=ln][k=q*8+0..7]; C/D: col=ln, row=q*4+r.
// ---------------------------------------------------------------------------
template <int IT, int JT>
__device__ __forceinline__ void mfma_half(
    f32x4 (&acc)[IT][JT], const bf16_t* Ah, const bf16_t* Bh,
    int wr, int wc, int q, int ln)
{
  bf16x8 a[IT], b[JT];
#pragma unroll
  for (int i = 0; i < IT; ++i)
    a[i] = *(const bf16x8*)(Ah + (wr + i * 16 + ln) * 32 + q * 8);
#pragma unroll
  for (int j = 0; j < JT; ++j)
    b[j] = *(const bf16x8*)(Bh + (wc + j * 16 + ln) * 32 + q * 8);
#pragma unroll
  for (int i = 0; i < IT; ++i)
#pragma unroll
    for (int j = 0; j < JT; ++j)
      acc[i][j] = __builtin_amdgcn_mfma_f32_16x16x32_bf16(a[i], b[j], acc[i][j], 0, 0, 0);
}

// ---------------------------------------------------------------------------
// k_obs_pre K-loop: 128x64 block tile, BK=128, 256 threads (4 waves, 2x2).
// As = 4 x [128][32] (32 KB), Bs = 4 x [64][32] (16 KB) -> 48 KB LDS
// -> 2 blocks/CU (verified round 7: obs path ~10 us/iter, was ~26).
// ---------------------------------------------------------------------------
__device__ __forceinline__ void loop_pre(
    f32x4 (&acc)[4][2],
    const bf16_t* __restrict__ A, const int* __restrict__ idx, int row0,
    const bf16_t* __restrict__ W, int ldw, int col0, int K,
    bf16_t* As, bf16_t* Bs)
{
  const int tid = threadIdx.x, wave = tid >> 6, lane = tid & 63;
  const int q = lane >> 4, ln = lane & 15;
  const int wr = (wave >> 1) * 64, wc = (wave & 1) * 32;
  const int srow = wave * 16 + (lane >> 2);   // 0..63
  const int skc  = (lane & 3) * 8;
  int ar0 = row0 + srow, ar1 = row0 + srow + 64;
  if (idx) { ar0 = idx[ar0]; ar1 = idx[ar1]; }
  const bf16_t* Ap0 = A + (size_t)ar0 * HS + skc;
  const bf16_t* Ap1 = A + (size_t)ar1 * HS + skc;
  const int brow = tid >> 2;                  // 0..63
  const bf16_t* Bp = W + (size_t)(col0 + brow) * ldw + skc;
  const int d0 = srow * 32 + skc, d1 = (srow + 64) * 32 + skc;
  const int db = brow * 32 + skc;

  for (int k0 = 0; k0 < K; k0 += 128) {
    __syncthreads();
#pragma unroll
    for (int s = 0; s < 4; ++s) {
      async16(Ap0 + k0 + s * 32, As + s * 4096 + d0);
      async16(Ap1 + k0 + s * 32, As + s * 4096 + d1);
      async16(Bp  + k0 + s * 32, Bs + s * 2048 + db);
    }
    __syncthreads();
#pragma unroll
    for (int s = 0; s < 4; ++s)
      mfma_half<4, 2>(acc, As + s * 4096, Bs + s * 2048, wr, wc, q, ln);
  }
}

// ---------------------------------------------------------------------------
// k_obs_post loss K-loop: 64x32 block tile, BK=64, 256 threads (4 waves 2x2).
// As = 2 x [64][32] (8 KB), Bs = 2 x [32][32] (4 KB).
// ---------------------------------------------------------------------------
__device__ __forceinline__ void loop_post(
    f32x4 (&acc)[2][1],
    const bf16_t* __restrict__ A, int row0,
    const bf16_t* __restrict__ W, int col0, int K,
    bf16_t* As, bf16_t* Bs)
{
  const int tid = threadIdx.x, wave = tid >> 6, lane = tid & 63;
  const int q = lane >> 4, ln = lane & 15;
  const int wr = (wave >> 1) * 32, wc = (wave & 1) * 16;
  const int srow = tid >> 2;                  // 0..63
  const int skc  = (tid & 3) * 8;
  const bf16_t* Ap = A + (size_t)(row0 + srow) * HS + skc;
  const int d = srow * 32 + skc;
  const int brow = (tid & 127) >> 2;          // 0..31 (tid<128 stages B)
  const bf16_t* Bp = W + (size_t)(col0 + brow) * HS + skc;
  const int dbB = brow * 32 + skc;

  for (int k0 = 0; k0 < K; k0 += 64) {
    __syncthreads();
    async16(Ap + k0,      As + d);
    async16(Ap + k0 + 32, As + 2048 + d);
    if (tid < 128) {                          // waves 0,1 fully active
      async16(Bp + k0,      Bs + dbB);
      async16(Bp + k0 + 32, Bs + 1024 + dbB);
    }
    __syncthreads();
    mfma_half<2, 1>(acc, As,        Bs,        wr, wc, q, ln);
    mfma_half<2, 1>(acc, As + 2048, Bs + 1024, wr, wc, q, ln);
  }
}

// ---------------------------------------------------------------------------
// Fused double-Euler kernel — ROUND-6 VERIFIED CONFIG (best measured ~51 us).
// 512 threads (8 waves); wave w owns 64-col stripe.
//
// Hs/Ts [64][512] bf16, XOR-swizzled: elem (row,col) at byte
//   row*1024 + ((((col*2)>>4) ^ (row&7))<<4) + ((col*2)&15).
// Operand-swapped MFMA: acc[i][jb] = mfma(Wfrag[i], Hfrag[jb], acc);
// each lane gets ONE h-row and 4 consecutive cols -> b64 epilogue LDS ops.
// W frag-major (k_cvt_frag); W-only single-sided ping-pong (1 slice ahead).
// Live set ~112 < the 128-VGPR cap of 512-thread builds.
//
// Register-cap ledger (measured): 512thr -> 128-VGPR cap; 1024thr -> 64-VGPR
// cap (R9: VGPR=64, WRITE 16.4->30.7 MB spill).  Double-sided pp spills at
// BOTH caps (R5: 143 live @128; R9: ~105 @64).  s_setprio: -20% (R7).
// Spill tripwire: WRITE_SIZE must stay 16384 KB.
// ---------------------------------------------------------------------------
__device__ __forceinline__ void gemm_k512(
    f32x4 (&acc)[4][4], const char* Tb, const bf16_t* __restrict__ Wf,
    int wc, int q, int ln)
{
  const int abase = ln * 1024;
  const int l3 = ln & 7;
  const bf16_t* Wl = Wf + (q * 512 + wc + ln) * 8;   // frag-major base
  bf16x8 wA[4], wB[4];
#pragma unroll
  for (int i = 0; i < 4; ++i) wA[i] = *(const bf16x8*)(Wl + i * 128);
#pragma unroll 1
  for (int ks2 = 0; ks2 < 8; ++ks2) {
    // prefetch W slice 2*ks2+1 -> wB; compute slice 2*ks2 with wA
    {
      const bf16_t* Wk = Wl + (2 * ks2 + 1) * 16384;
#pragma unroll
      for (int i = 0; i < 4; ++i) wB[i] = *(const bf16x8*)(Wk + i * 128);
    }
    {
      bf16x8 t[4];
      const int coff = (((2 * ks2) * 4 + q) ^ l3) << 4;
#pragma unroll
      for (int jb = 0; jb < 4; ++jb)
        t[jb] = *(const bf16x8*)(Tb + jb * 16384 + abase + coff);
#pragma unroll
      for (int i = 0; i < 4; ++i)
#pragma unroll
        for (int jb = 0; jb < 4; ++jb)
          acc[i][jb] = __builtin_amdgcn_mfma_f32_16x16x32_bf16(wA[i], t[jb], acc[i][jb], 0, 0, 0);
    }
    // prefetch W slice 2*ks2+2 -> wA (guarded); compute 2*ks2+1 with wB
    if (ks2 < 7) {
      const bf16_t* Wk = Wl + (2 * ks2 + 2) * 16384;
#pragma unroll
      for (int i = 0; i < 4; ++i) wA[i] = *(const bf16x8*)(Wk + i * 128);
    }
    {
      bf16x8 t[4];
      const int coff = (((2 * ks2 + 1) * 4 + q) ^ l3) << 4;
#pragma unroll
      for (int jb = 0; jb < 4; ++jb)
        t[jb] = *(const bf16x8*)(Tb + jb * 16384 + abase + coff);
#pragma unroll
      for (int i = 0; i < 4; ++i)
#pragma unroll
        for (int jb = 0; jb < 4; ++jb)
          acc[i][jb] = __builtin_amdgcn_mfma_f32_16x16x32_bf16(wB[i], t[jb], acc[i][jb], 0, 0, 0);
    }
  }
}

__global__ __launch_bounds__(512)
__attribute__((amdgpu_waves_per_eu(2, 2)))
void k_euler2(
    bf16_t* __restrict__ h,
    const bf16_t* __restrict__ Wo1, const float* __restrict__ bo1,
    const bf16_t* __restrict__ Wo2, const float* __restrict__ bo2)
{
  __shared__ __align__(16) char Hs[64 * 1024];
  __shared__ __align__(16) char Ts[64 * 1024];
  const int tid = threadIdx.x;
  const int wave = tid >> 6, lane = tid & 63;
  const int q = lane >> 4, ln = lane & 15;
  const int wc = wave * 64;
  const int r0 = blockIdx.x * 64;

  // stage h -> Hs (swizzled): 4096 16B chunks, 8 per thread, coalesced.
#pragma unroll
  for (int u = 0; u < 8; ++u) {
    const int g = u * 512 + tid;
    const int row = g >> 6, c16 = g & 63;
    *(uint4*)(Hs + row * 1024 + ((c16 ^ (row & 7)) << 4)) =
        *(const uint4*)(h + (size_t)(r0 + row) * HS + c16 * 8);
  }
  __syncthreads();

#pragma unroll 1
  for (int step = 0; step < 2; ++step) {
    // T = tanh(h @ Wo1^T + bo1)
    {
      f32x4 acc[4][4] = {};
      gemm_k512(acc, Hs, Wo1, wc, q, ln);
#pragma unroll
      for (int i = 0; i < 4; ++i) {
        const int c0 = wc + i * 16 + q * 4;
        const float4 b4 = *(const float4*)(bo1 + c0);
        const int cb = c0 * 2;
#pragma unroll
        for (int jb = 0; jb < 4; ++jb) {
          const int row = jb * 16 + ln;
          __attribute__((aligned(8))) bf16_t pk[4];
          pk[0] = __float2bfloat16(fast_tanh(acc[i][jb][0] + b4.x));
          pk[1] = __float2bfloat16(fast_tanh(acc[i][jb][1] + b4.y));
          pk[2] = __float2bfloat16(fast_tanh(acc[i][jb][2] + b4.z));
          pk[3] = __float2bfloat16(fast_tanh(acc[i][jb][3] + b4.w));
          *(uint2*)(Ts + row * 1024 + (((cb >> 4) ^ (row & 7)) << 4) + (cb & 15)) =
              *(const uint2*)pk;
        }
      }
    }
    __syncthreads();   // Ts complete (and all Hs reads of this step done)
    // h = h + DT * (T @ Wo2^T + bo2)
    {
      f32x4 acc[4][4] = {};
      gemm_k512(acc, Ts, Wo2, wc, q, ln);
#pragma unroll
      for (int i = 0; i < 4; ++i) {
        const int c0 = wc + i * 16 + q * 4;
        const float4 b4 = *(const float4*)(bo2 + c0);
        const int cb = c0 * 2;
#pragma unroll
        for (int jb = 0; jb < 4; ++jb) {
          const int row = jb * 16 + ln;
          char* p = Hs + row * 1024 + (((cb >> 4) ^ (row & 7)) << 4) + (cb & 15);
          uint2 ov = *(const uint2*)p;
          const bf16_t* ob = (const bf16_t*)&ov;
          __attribute__((aligned(8))) bf16_t pk[4];
          pk[0] = __float2bfloat16(__bfloat162float(ob[0]) + DTC * (acc[i][jb][0] + b4.x));
          pk[1] = __float2bfloat16(__bfloat162float(ob[1]) + DTC * (acc[i][jb][1] + b4.y));
          pk[2] = __float2bfloat16(__bfloat162float(ob[2]) + DTC * (acc[i][jb][2] + b4.z));
          pk[3] = __float2bfloat16(__bfloat162float(ob[3]) + DTC * (acc[i][jb][3] + b4.w));
          *(uint2*)p = *(const uint2*)pk;
        }
      }
    }
    __syncthreads();   // Hs updated; safe for next step's GEMM1 / final store
  }

  // store Hs -> h
#pragma unroll
  for (int u = 0; u < 8; ++u) {
    const int g = u * 512 + tid;
    const int row = g >> 6, c16 = g & 63;
    *(uint4*)(h + (size_t)(r0 + row) * HS + c16 * 8) =
        *(const uint4*)(Hs + row * 1024 + ((c16 ^ (row & 7)) << 4));
  }
}

// ---------------------------------------------------------------------------
// Fused: z==0 -> tmpE = relu(h[idx] @ Wp1^T + bp1)
//        z==1 -> hnewE = tanh(Xk @ Wih^T + b_ih + h[idx] @ Whh^T + b_hh)
// Grid (32, 8, 2) = 512 blocks of (128 rows x 64 cols), 48 KB LDS
// -> 2 blocks/CU for latency overlap.  (verified round 7)
__global__ __launch_bounds__(256) void k_obs_pre(
    const bf16_t* __restrict__ h, const int* __restrict__ idx,
    const bf16_t* __restrict__ Wp1, const float* __restrict__ bp1,
    bf16_t* __restrict__ tmpE,
    const float* __restrict__ Xk,
    const bf16_t* __restrict__ Wih, const float* __restrict__ b_ih,
    const bf16_t* __restrict__ Whh, const float* __restrict__ b_hh,
    bf16_t* __restrict__ hnewE)
{
  __shared__ bf16_t As[128 * 128], Bs[64 * 128];
  f32x4 acc[4][2] = {};
  const int tid = threadIdx.x, wave = tid >> 6, lane = tid & 63;
  const int q = lane >> 4, ln = lane & 15;
  const int wr = (wave >> 1) * 64, wc = (wave & 1) * 32;
  const int row0 = blockIdx.x * 128, col0 = blockIdx.y * 64;

  if (blockIdx.z == 0) {
    loop_pre(acc, h, idx, row0, Wp1, HS, col0, HS, As, Bs);
#pragma unroll
    for (int j = 0; j < 2; ++j) {
      const int c = col0 + wc + j * 16 + ln;
      const float bj = bp1[c];
#pragma unroll
      for (int i = 0; i < 4; ++i)
#pragma unroll
        for (int r = 0; r < 4; ++r) {
          const int rw = row0 + wr + i * 16 + q * 4 + r;
          const float v = acc[i][j][r] + bj;
          tmpE[(size_t)rw * HS + c] = __float2bfloat16(v > 0.f ? v : 0.f);
        }
    }
  } else {
    // phase 1: Xk (fp32) @ Wih^T, K = DS = 128, single BK=128 barrier pair
    {
      const int brow = tid >> 2;
      const int skc  = (tid & 3) * 8;
      const bf16_t* Bp = Wih + (size_t)(col0 + brow) * DS + skc;
      const int db = brow * 32 + skc;
      const int xr = tid >> 1, xh = (tid & 1) * 16;
#pragma unroll
      for (int s = 0; s < 4; ++s)
        async16(Bp + s * 32, Bs + s * 2048 + db);
#pragma unroll
      for (int s = 0; s < 4; ++s) {
        const float* src = Xk + (size_t)(row0 + xr) * DS + s * 32 + xh;
        __attribute__((aligned(16))) bf16_t buf[16];
#pragma unroll
        for (int u = 0; u < 16; ++u) buf[u] = __float2bfloat16(src[u]);
        *(uint4*)(As + s * 4096 + xr * 32 + xh)     = *(const uint4*)buf;
        *(uint4*)(As + s * 4096 + xr * 32 + xh + 8) = *(const uint4*)(buf + 8);
      }
      __syncthreads();
#pragma unroll
      for (int s = 0; s < 4; ++s)
        mfma_half<4, 2>(acc, As + s * 4096, Bs + s * 2048, wr, wc, q, ln);
    }
    // phase 2: h[idx] @ Whh^T, K = HS (loop_pre's leading barrier protects As)
    loop_pre(acc, h, idx, row0, Whh, HS, col0, HS, As, Bs);
#pragma unroll
    for (int j = 0; j < 2; ++j) {
      const int c = col0 + wc + j * 16 + ln;
      const float bj = b_ih[c] + b_hh[c];
#pragma unroll
      for (int i = 0; i < 4; ++i)
#pragma unroll
        for (int r = 0; r < 4; ++r) {
          const int rw = row0 + wr + i * 16 + q * 4 + r;
          hnewE[(size_t)rw * HS + c] = __float2bfloat16(fast_tanh(acc[i][j][r] + bj));
        }
    }
  }
}

// Fused: blocks [0,256) -> loss GEMM (64x32 tiles, full GPU);
//        [256,1280) -> scatter
__global__ __launch_bounds__(256) void k_obs_post(
    const bf16_t* __restrict__ tmpE, const bf16_t* __restrict__ Wp2,
    const float* __restrict__ bp2, const float* __restrict__ X,
    const float* __restrict__ Mm, float* __restrict__ accum,
    bf16_t* __restrict__ h, const bf16_t* __restrict__ hnewE,
    const int* __restrict__ idx)
{
  const int bid = blockIdx.x;
  if (bid >= 256) {
    const int t  = (bid - 256) * 256 + threadIdx.x;
    const int r  = t >> 6;
    const int c8 = (t & 63) * 8;
    const int gr = idx[r];
    *(uint4*)(h + (size_t)gr * HS + c8) = *(const uint4*)(hnewE + (size_t)r * HS + c8);
    return;
  }
  __shared__ bf16_t As[64 * 64], Bs[32 * 64];
  f32x4 acc[2][1] = {};
  const int wave = threadIdx.x >> 6, lane = threadIdx.x & 63;
  const int q = lane >> 4, ln = lane & 15;
  const int wr = (wave >> 1) * 32, wc = (wave & 1) * 16;
  const int row0 = (bid >> 2) * 64, col0 = (bid & 3) * 32;
  loop_post(acc, tmpE, row0, Wp2, col0, HS, As, Bs);
  float ls = 0.f;
  {
    const int c = col0 + wc + ln;
    const float bj = bp2[c];
#pragma unroll
    for (int i = 0; i < 2; ++i)
#pragma unroll
      for (int r = 0; r < 4; ++r) {
        const int rw = row0 + wr + i * 16 + q * 4 + r;
        const float p = acc[i][0][r] + bj;
        const size_t o = (size_t)rw * DS + c;
        ls += fabsf(X[o] - p) * Mm[o];
      }
  }
#pragma unroll
  for (int off = 32; off > 0; off >>= 1) ls += __shfl_down(ls, off);
  __shared__ float red[4];
  if (lane == 0) red[wave] = ls;
  __syncthreads();
  if (threadIdx.x == 0) atomicAdd(accum, red[0] + red[1] + red[2] + red[3]);
}

__global__ void k_cvt(const float* __restrict__ s, bf16_t* __restrict__ d, int n)
{
  const int i = blockIdx.x * 256 + threadIdx.x;
  if (i * 4 < n) {
    const float4 v = ((const float4*)s)[i];
    d[i * 4 + 0] = __float2bfloat16(v.x);
    d[i * 4 + 1] = __float2bfloat16(v.y);
    d[i * 4 + 2] = __float2bfloat16(v.z);
    d[i * 4 + 3] = __float2bfloat16(v.w);
  }
}

// fp32 [512][512] row-major -> frag-major bf16: chunk (c,r) at elems
// (c*512 + r)*8 holds W[r][c*8 .. c*8+8).  t = c*512 + r, coalesced stores.
__global__ void k_cvt_frag(const float* __restrict__ s, bf16_t* __restrict__ d)
{
  const int t = blockIdx.x * 256 + threadIdx.x;
  const int r = t & 511, c = t >> 9;
  const float4 v0 = *(const float4*)(s + (size_t)r * HS + c * 8);
  const float4 v1 = *(const float4*)(s + (size_t)r * HS + c * 8 + 4);
  __attribute__((aligned(16))) bf16_t buf[8];
  buf[0] = __float2bfloat16(v0.x); buf[1] = __float2bfloat16(v0.y);
  buf[2] = __float2bfloat16(v0.z); buf[3] = __float2bfloat16(v0.w);
  buf[4] = __float2bfloat16(v1.x); buf[5] = __float2bfloat16(v1.y);
  buf[6] = __float2bfloat16(v1.z); buf[7] = __float2bfloat16(v1.w);
  *(uint4*)(d + (size_t)t * 8) = *(const uint4*)buf;
}

__global__ void k_zero(float* __restrict__ p, size_t n4)
{
  size_t i = (size_t)blockIdx.x * blockDim.x + threadIdx.x;
  const size_t st = (size_t)gridDim.x * blockDim.x;
  const float4 z = {0.f, 0.f, 0.f, 0.f};
  for (; i < n4; i += st) ((float4*)p)[i] = z;
}

__global__ void k_zero_accum(float* accum)
{
  if (threadIdx.x < 2) accum[threadIdx.x] = 0.f;
}

__global__ void k_sum(const float* __restrict__ M, size_t n4, float* __restrict__ accum)
{
  __shared__ float red[256];
  float s = 0.f;
  for (size_t i = (size_t)blockIdx.x * blockDim.x + threadIdx.x; i < n4;
       i += (size_t)gridDim.x * blockDim.x) {
    const float4 v = ((const float4*)M)[i];
    s += v.x + v.y + v.z + v.w;
  }
  red[threadIdx.x] = s;
  __syncthreads();
  for (int st = 128; st > 0; st >>= 1) {
    if (threadIdx.x < st) red[threadIdx.x] += red[threadIdx.x + st];
    __syncthreads();
  }
  if (threadIdx.x == 0) atomicAdd(accum + 1, red[0]);
}

__global__ void k_final(const float* __restrict__ accum, float* __restrict__ out)
{
  out[0] = accum[0];
  out[1] = accum[0] / accum[1];
}

// ---------------------------------------------------------------------------
extern "C" void kernel_launch(void* const* d_in, const int* in_sizes, int n_in,
                              void* d_out, int out_size, void* d_ws, size_t ws_size,
                              hipStream_t stream)
{
  const float* X    = (const float*)d_in[0];
  const float* M    = (const float*)d_in[1];
  const int*   bidx = (const int*)d_in[2];
  const float* W_ih = (const float*)d_in[3];
  const float* b_ih = (const float*)d_in[4];
  const float* W_hh = (const float*)d_in[5];
  const float* b_hh = (const float*)d_in[6];
  const float* Wo1  = (const float*)d_in[7];
  const float* bo1  = (const float*)d_in[8];
  const float* Wo2  = (const float*)d_in[9];
  const float* bo2  = (const float*)d_in[10];
  const float* Wp1  = (const float*)d_in[11];
  const float* bp1  = (const float*)d_in[12];
  const float* Wp2  = (const float*)d_in[13];
  const float* bp2  = (const float*)d_in[14];
  float* out = (float*)d_out;

  char* w = (char*)d_ws;
  bf16_t* h     = (bf16_t*)w;                         w += (size_t)NS * HS * 2;
  bf16_t* tmpE  = (bf16_t*)w;                         w += (size_t)ES * HS * 2;
  bf16_t* hnewE = (bf16_t*)w;                         w += (size_t)ES * HS * 2;
  bf16_t* wWo1  = (bf16_t*)w;                         w += (size_t)HS * HS * 2;
  bf16_t* wWo2  = (bf16_t*)w;                         w += (size_t)HS * HS * 2;
  bf16_t* wWp1  = (bf16_t*)w;                         w += (size_t)HS * HS * 2;
  bf16_t* wWp2  = (bf16_t*)w;                         w += (size_t)DS * HS * 2;
  bf16_t* wWih  = (bf16_t*)w;                         w += (size_t)HS * DS * 2;
  bf16_t* wWhh  = (bf16_t*)w;                         w += (size_t)HS * HS * 2;
  float*  accum = (float*)w;

  k_zero<<<2048, 256, 0, stream>>>((float*)h, (size_t)NS * HS * 2 / 16);
  k_zero_accum<<<1, 64, 0, stream>>>(accum);
  k_sum<<<2048, 256, 0, stream>>>(M, (size_t)KOBS * ES * DS / 4, accum);
  k_cvt_frag<<<128, 256, 0, stream>>>(Wo1, wWo1);   // frag-major for k_euler2
  k_cvt_frag<<<128, 256, 0, stream>>>(Wo2, wWo2);
  k_cvt<<<256, 256, 0, stream>>>(Wp1, wWp1, HS * HS);
  k_cvt<<<64, 256, 0, stream>>>(Wp2, wWp2, DS * HS);
  k_cvt<<<64, 256, 0, stream>>>(W_ih, wWih, HS * DS);
  k_cvt<<<256, 256, 0, stream>>>(W_hh, wWhh, HS * HS);

  const dim3 gPre(ES / 128, HS / 64, 2);       // 32 x 8 x 2 = 512 blocks
  const int  gPost = 256 + ES * HS / 8 / 256;  // 256 loss + 1024 scatter

  for (int k = 0; k < KOBS; ++k) {
    const int*   idx = bidx + (size_t)k * ES;
    const float* Xk  = X + (size_t)k * ES * DS;
    const float* Mk  = M + (size_t)k * ES * DS;

    // both Euler steps fused; h tile resident in LDS (grid = 256 = 1 block/CU)
    k_euler2<<<NS / 64, 512, 0, stream>>>(h, wWo1, bo1, wWo2, bo2);
    k_obs_pre <<<gPre, 256, 0, stream>>>(h, idx, wWp1, bp1, tmpE,
                                         Xk, wWih, b_ih, wWhh, b_hh, hnewE);
    k_obs_post<<<gPost, 256, 0, stream>>>(tmpE, wWp2, bp2, Xk, Mk, accum,
                                          h, hnewE, idx);
  }

  k_final<<<1, 1, 0, stream>>>(accum, out);
}

// Round 11
// 2503.707 us; speedup vs baseline: 1.1658x; 1.1349x over previous
//
#include <hip/hip_runtime.h>
#include <hip/hip_bf16.h>
#include <cstddef>
#include <cstdint>

#define NS   16384
#define HS   512
#define DS   128
#define KOBS 40
#define ES   4096
#define DTC  0.05f

typedef __bf16 bf16x8 __attribute__((ext_vector_type(8)));
typedef float  f32x4  __attribute__((ext_vector_type(4)));
typedef __hip_bfloat16 bf16_t;

__device__ __forceinline__ void async16(const void* g, void* l)
{
  __builtin_amdgcn_global_load_lds(
      (const __attribute__((address_space(1))) unsigned int*)g,
      (__attribute__((address_space(3))) unsigned int*)l, 16, 0, 0);
}

// fast tanh: 1 - 2/(1+e^{2x}); |err| ~1e-7 rel, far below bf16 quantization.
__device__ __forceinline__ float fast_tanh(float x)
{
  return 1.f - 2.f / (1.f + __expf(2.f * x));
}

// ---------------------------------------------------------------------------
// One BK=32 half-step from [rows][32] LDS tiles (64B row stride).
// A-frag: lane holds A[m=ln][k=q*8+0..7]; C/D: col=ln, row=q*4+r.
// ---------------------------------------------------------------------------
template <int IT, int JT>
__device__ __forceinline__ void mfma_half(
    f32x4 (&acc)[IT][JT], const bf16_t* Ah, const bf16_t* Bh,
    int wr, int wc, int q, int ln)
{
  bf16x8 a[IT], b[JT];
#pragma unroll
  for (int i = 0; i < IT; ++i)
    a[i] = *(const bf16x8*)(Ah + (wr + i * 16 + ln) * 32 + q * 8);
#pragma unroll
  for (int j = 0; j < JT; ++j)
    b[j] = *(const bf16x8*)(Bh + (wc + j * 16 + ln) * 32 + q * 8);
#pragma unroll
  for (int i = 0; i < IT; ++i)
#pragma unroll
    for (int j = 0; j < JT; ++j)
      acc[i][j] = __builtin_amdgcn_mfma_f32_16x16x32_bf16(a[i], b[j], acc[i][j], 0, 0, 0);
}

// ---------------------------------------------------------------------------
// k_obs_fused pre K-loop: 128x64 block tile, BK=128, 256 threads (4 waves).
// As = 4 x [128][32] (32 KB), Bs = 4 x [64][32] (16 KB) -> 48 KB LDS
// -> 2 blocks/CU (verified round 7).
// ---------------------------------------------------------------------------
__device__ __forceinline__ void loop_pre(
    f32x4 (&acc)[4][2],
    const bf16_t* __restrict__ A, const int* __restrict__ idx, int row0,
    const bf16_t* __restrict__ W, int ldw, int col0, int K,
    bf16_t* As, bf16_t* Bs)
{
  const int tid = threadIdx.x, wave = tid >> 6, lane = tid & 63;
  const int q = lane >> 4, ln = lane & 15;
  const int wr = (wave >> 1) * 64, wc = (wave & 1) * 32;
  const int srow = wave * 16 + (lane >> 2);   // 0..63
  const int skc  = (lane & 3) * 8;
  int ar0 = row0 + srow, ar1 = row0 + srow + 64;
  if (idx) { ar0 = idx[ar0]; ar1 = idx[ar1]; }
  const bf16_t* Ap0 = A + (size_t)ar0 * HS + skc;
  const bf16_t* Ap1 = A + (size_t)ar1 * HS + skc;
  const int brow = tid >> 2;                  // 0..63
  const bf16_t* Bp = W + (size_t)(col0 + brow) * ldw + skc;
  const int d0 = srow * 32 + skc, d1 = (srow + 64) * 32 + skc;
  const int db = brow * 32 + skc;

  for (int k0 = 0; k0 < K; k0 += 128) {
    __syncthreads();
#pragma unroll
    for (int s = 0; s < 4; ++s) {
      async16(Ap0 + k0 + s * 32, As + s * 4096 + d0);
      async16(Ap1 + k0 + s * 32, As + s * 4096 + d1);
      async16(Bp  + k0 + s * 32, Bs + s * 2048 + db);
    }
    __syncthreads();
#pragma unroll
    for (int s = 0; s < 4; ++s)
      mfma_half<4, 2>(acc, As + s * 4096, Bs + s * 2048, wr, wc, q, ln);
  }
}

// ---------------------------------------------------------------------------
// loss K-loop: 64x32 block tile, BK=64, 256 threads (4 waves 2x2).
// As = 2 x [64][32] (8 KB), Bs = 2 x [32][32] (4 KB).
// ---------------------------------------------------------------------------
__device__ __forceinline__ void loop_post(
    f32x4 (&acc)[2][1],
    const bf16_t* __restrict__ A, int row0,
    const bf16_t* __restrict__ W, int col0, int K,
    bf16_t* As, bf16_t* Bs)
{
  const int tid = threadIdx.x, wave = tid >> 6, lane = tid & 63;
  const int q = lane >> 4, ln = lane & 15;
  const int wr = (wave >> 1) * 32, wc = (wave & 1) * 16;
  const int srow = tid >> 2;                  // 0..63
  const int skc  = (tid & 3) * 8;
  const bf16_t* Ap = A + (size_t)(row0 + srow) * HS + skc;
  const int d = srow * 32 + skc;
  const int brow = (tid & 127) >> 2;          // 0..31 (tid<128 stages B)
  const bf16_t* Bp = W + (size_t)(col0 + brow) * HS + skc;
  const int dbB = brow * 32 + skc;

  for (int k0 = 0; k0 < K; k0 += 64) {
    __syncthreads();
    async16(Ap + k0,      As + d);
    async16(Ap + k0 + 32, As + 2048 + d);
    if (tid < 128) {                          // waves 0,1 fully active
      async16(Bp + k0,      Bs + dbB);
      async16(Bp + k0 + 32, Bs + 1024 + dbB);
    }
    __syncthreads();
    mfma_half<2, 1>(acc, As,        Bs,        wr, wc, q, ln);
    mfma_half<2, 1>(acc, As + 2048, Bs + 1024, wr, wc, q, ln);
  }
}

// loss tile t in [0,256): rows (t>>2)*64, cols (t&3)*32 of |X - p|*M.
__device__ __forceinline__ void loss_tile(
    int t, const bf16_t* __restrict__ tmpP,
    const bf16_t* __restrict__ Wp2, const float* __restrict__ bp2,
    const float* __restrict__ X, const float* __restrict__ Mm,
    float* __restrict__ accum, bf16_t* As, bf16_t* Bs, float* red)
{
  f32x4 acc[2][1] = {};
  const int wave = threadIdx.x >> 6, lane = threadIdx.x & 63;
  const int q = lane >> 4, ln = lane & 15;
  const int wr = (wave >> 1) * 32, wc = (wave & 1) * 16;
  const int row0 = (t >> 2) * 64, col0 = (t & 3) * 32;
  loop_post(acc, tmpP, row0, Wp2, col0, HS, As, Bs);
  float ls = 0.f;
  const int c = col0 + wc + ln;
  const float bj = bp2[c];
#pragma unroll
  for (int i = 0; i < 2; ++i)
#pragma unroll
    for (int r = 0; r < 4; ++r) {
      const int rw = row0 + wr + i * 16 + q * 4 + r;
      const float p = acc[i][0][r] + bj;
      const size_t o = (size_t)rw * DS + c;
      ls += fabsf(X[o] - p) * Mm[o];
    }
#pragma unroll
  for (int off = 32; off > 0; off >>= 1) ls += __shfl_down(ls, off);
  if (lane == 0) red[wave] = ls;
  __syncthreads();
  if (threadIdx.x == 0) atomicAdd(accum, red[0] + red[1] + red[2] + red[3]);
}

// ---------------------------------------------------------------------------
// Fused double-Euler kernel — ROUND-6 VERIFIED CONFIG (best measured ~47 us),
// plus inv-index gather staging (replaces the separate scatter pass):
// row gr loads from hnewE[inv[gr]] when inv[gr]>=0 (RNN-updated last obs),
// else from h[gr].  Branch is wave-uniform (one row per 64 lanes).
//
// Hs/Ts [64][512] bf16, XOR-swizzled; operand-swapped MFMA; W frag-major;
// W-only single-sided ping-pong.  Register-cap ledger (measured): 512thr ->
// 128-VGPR cap; 1024thr -> 64-cap (R9 spill); double-sided pp spills at both
// caps (R5/R9); s_setprio -20% (R7).  Spill tripwire: WRITE_SIZE 16384 KB.
// ---------------------------------------------------------------------------
__device__ __forceinline__ void gemm_k512(
    f32x4 (&acc)[4][4], const char* Tb, const bf16_t* __restrict__ Wf,
    int wc, int q, int ln)
{
  const int abase = ln * 1024;
  const int l3 = ln & 7;
  const bf16_t* Wl = Wf + (q * 512 + wc + ln) * 8;   // frag-major base
  bf16x8 wA[4], wB[4];
#pragma unroll
  for (int i = 0; i < 4; ++i) wA[i] = *(const bf16x8*)(Wl + i * 128);
#pragma unroll 1
  for (int ks2 = 0; ks2 < 8; ++ks2) {
    {
      const bf16_t* Wk = Wl + (2 * ks2 + 1) * 16384;
#pragma unroll
      for (int i = 0; i < 4; ++i) wB[i] = *(const bf16x8*)(Wk + i * 128);
    }
    {
      bf16x8 t[4];
      const int coff = (((2 * ks2) * 4 + q) ^ l3) << 4;
#pragma unroll
      for (int jb = 0; jb < 4; ++jb)
        t[jb] = *(const bf16x8*)(Tb + jb * 16384 + abase + coff);
#pragma unroll
      for (int i = 0; i < 4; ++i)
#pragma unroll
        for (int jb = 0; jb < 4; ++jb)
          acc[i][jb] = __builtin_amdgcn_mfma_f32_16x16x32_bf16(wA[i], t[jb], acc[i][jb], 0, 0, 0);
    }
    if (ks2 < 7) {
      const bf16_t* Wk = Wl + (2 * ks2 + 2) * 16384;
#pragma unroll
      for (int i = 0; i < 4; ++i) wA[i] = *(const bf16x8*)(Wk + i * 128);
    }
    {
      bf16x8 t[4];
      const int coff = (((2 * ks2 + 1) * 4 + q) ^ l3) << 4;
#pragma unroll
      for (int jb = 0; jb < 4; ++jb)
        t[jb] = *(const bf16x8*)(Tb + jb * 16384 + abase + coff);
#pragma unroll
      for (int i = 0; i < 4; ++i)
#pragma unroll
        for (int jb = 0; jb < 4; ++jb)
          acc[i][jb] = __builtin_amdgcn_mfma_f32_16x16x32_bf16(wB[i], t[jb], acc[i][jb], 0, 0, 0);
    }
  }
}

__global__ __launch_bounds__(512)
__attribute__((amdgpu_waves_per_eu(2, 2)))
void k_euler2(
    bf16_t* __restrict__ h,
    const bf16_t* __restrict__ Wo1, const float* __restrict__ bo1,
    const bf16_t* __restrict__ Wo2, const float* __restrict__ bo2,
    const int* __restrict__ invk, const bf16_t* __restrict__ hnewE)
{
  __shared__ __align__(16) char Hs[64 * 1024];
  __shared__ __align__(16) char Ts[64 * 1024];
  const int tid = threadIdx.x;
  const int wave = tid >> 6, lane = tid & 63;
  const int q = lane >> 4, ln = lane & 15;
  const int wc = wave * 64;
  const int r0 = blockIdx.x * 64;

  // stage h -> Hs (swizzled), gathering RNN-updated rows from hnewE via inv.
#pragma unroll
  for (int u = 0; u < 8; ++u) {
    const int g = u * 512 + tid;
    const int row = g >> 6, c16 = g & 63;
    const int gr = r0 + row;
    const int iv = invk[gr];                    // wave-uniform per row
    const bf16_t* srcp = (iv >= 0) ? (hnewE + (size_t)iv * HS)
                                   : (h + (size_t)gr * HS);
    *(uint4*)(Hs + row * 1024 + ((c16 ^ (row & 7)) << 4)) =
        *(const uint4*)(srcp + c16 * 8);
  }
  __syncthreads();

#pragma unroll 1
  for (int step = 0; step < 2; ++step) {
    // T = tanh(h @ Wo1^T + bo1)
    {
      f32x4 acc[4][4] = {};
      gemm_k512(acc, Hs, Wo1, wc, q, ln);
#pragma unroll
      for (int i = 0; i < 4; ++i) {
        const int c0 = wc + i * 16 + q * 4;
        const float4 b4 = *(const float4*)(bo1 + c0);
        const int cb = c0 * 2;
#pragma unroll
        for (int jb = 0; jb < 4; ++jb) {
          const int row = jb * 16 + ln;
          __attribute__((aligned(8))) bf16_t pk[4];
          pk[0] = __float2bfloat16(fast_tanh(acc[i][jb][0] + b4.x));
          pk[1] = __float2bfloat16(fast_tanh(acc[i][jb][1] + b4.y));
          pk[2] = __float2bfloat16(fast_tanh(acc[i][jb][2] + b4.z));
          pk[3] = __float2bfloat16(fast_tanh(acc[i][jb][3] + b4.w));
          *(uint2*)(Ts + row * 1024 + (((cb >> 4) ^ (row & 7)) << 4) + (cb & 15)) =
              *(const uint2*)pk;
        }
      }
    }
    __syncthreads();   // Ts complete (and all Hs reads of this step done)
    // h = h + DT * (T @ Wo2^T + bo2)
    {
      f32x4 acc[4][4] = {};
      gemm_k512(acc, Ts, Wo2, wc, q, ln);
#pragma unroll
      for (int i = 0; i < 4; ++i) {
        const int c0 = wc + i * 16 + q * 4;
        const float4 b4 = *(const float4*)(bo2 + c0);
        const int cb = c0 * 2;
#pragma unroll
        for (int jb = 0; jb < 4; ++jb) {
          const int row = jb * 16 + ln;
          char* p = Hs + row * 1024 + (((cb >> 4) ^ (row & 7)) << 4) + (cb & 15);
          uint2 ov = *(const uint2*)p;
          const bf16_t* ob = (const bf16_t*)&ov;
          __attribute__((aligned(8))) bf16_t pk[4];
          pk[0] = __float2bfloat16(__bfloat162float(ob[0]) + DTC * (acc[i][jb][0] + b4.x));
          pk[1] = __float2bfloat16(__bfloat162float(ob[1]) + DTC * (acc[i][jb][1] + b4.y));
          pk[2] = __float2bfloat16(__bfloat162float(ob[2]) + DTC * (acc[i][jb][2] + b4.z));
          pk[3] = __float2bfloat16(__bfloat162float(ob[3]) + DTC * (acc[i][jb][3] + b4.w));
          *(uint2*)p = *(const uint2*)pk;
        }
      }
    }
    __syncthreads();   // Hs updated; safe for next step's GEMM1 / final store
  }

  // store Hs -> h
#pragma unroll
  for (int u = 0; u < 8; ++u) {
    const int g = u * 512 + tid;
    const int row = g >> 6, c16 = g & 63;
    *(uint4*)(h + (size_t)(r0 + row) * HS + c16 * 8) =
        *(const uint4*)(Hs + row * 1024 + ((c16 ^ (row & 7)) << 4));
  }
}

// ---------------------------------------------------------------------------
// Fused obs kernel, grid (32, 8, 3):
//  z==0 -> tmpE = relu(h[idx] @ Wp1^T + bp1)            (128x64 tiles)
//  z==1 -> hnewE = tanh(Xk @ Wih^T + b_ih + h[idx] @ Whh^T + b_hh)
//  z==2 -> loss of PREVIOUS step from tmpPrev (skipped when Xp==nullptr).
// z2 runs as separate BLOCKS (own barrier count is fine) and reads the
// other tmpE parity buffer -> no race with z0's writes.  48 KB LDS.
__global__ __launch_bounds__(256) void k_obs_fused(
    const bf16_t* __restrict__ h, const int* __restrict__ idx,
    const bf16_t* __restrict__ Wp1, const float* __restrict__ bp1,
    bf16_t* __restrict__ tmpE,
    const float* __restrict__ Xk,
    const bf16_t* __restrict__ Wih, const float* __restrict__ b_ih,
    const bf16_t* __restrict__ Whh, const float* __restrict__ b_hh,
    bf16_t* __restrict__ hnewE,
    const bf16_t* __restrict__ tmpPrev,
    const bf16_t* __restrict__ Wp2, const float* __restrict__ bp2,
    const float* __restrict__ Xp, const float* __restrict__ Mp,
    float* __restrict__ accum)
{
  __shared__ bf16_t As[128 * 128], Bs[64 * 128];
  __shared__ float red[4];
  const int tid = threadIdx.x, wave = tid >> 6, lane = tid & 63;
  const int q = lane >> 4, ln = lane & 15;

  if (blockIdx.z == 2) {
    if (Xp == nullptr) return;
    loss_tile(blockIdx.x * 8 + blockIdx.y, tmpPrev, Wp2, bp2, Xp, Mp,
              accum, As, Bs, red);
    return;
  }

  f32x4 acc[4][2] = {};
  const int wr = (wave >> 1) * 64, wc = (wave & 1) * 32;
  const int row0 = blockIdx.x * 128, col0 = blockIdx.y * 64;

  if (blockIdx.z == 0) {
    loop_pre(acc, h, idx, row0, Wp1, HS, col0, HS, As, Bs);
#pragma unroll
    for (int j = 0; j < 2; ++j) {
      const int c = col0 + wc + j * 16 + ln;
      const float bj = bp1[c];
#pragma unroll
      for (int i = 0; i < 4; ++i)
#pragma unroll
        for (int r = 0; r < 4; ++r) {
          const int rw = row0 + wr + i * 16 + q * 4 + r;
          const float v = acc[i][j][r] + bj;
          tmpE[(size_t)rw * HS + c] = __float2bfloat16(v > 0.f ? v : 0.f);
        }
    }
  } else {
    // phase 1: Xk (fp32) @ Wih^T, K = DS = 128, single BK=128 barrier pair
    {
      const int brow = tid >> 2;
      const int skc  = (tid & 3) * 8;
      const bf16_t* Bp = Wih + (size_t)(col0 + brow) * DS + skc;
      const int db = brow * 32 + skc;
      const int xr = tid >> 1, xh = (tid & 1) * 16;
#pragma unroll
      for (int s = 0; s < 4; ++s)
        async16(Bp + s * 32, Bs + s * 2048 + db);
#pragma unroll
      for (int s = 0; s < 4; ++s) {
        const float* src = Xk + (size_t)(row0 + xr) * DS + s * 32 + xh;
        __attribute__((aligned(16))) bf16_t buf[16];
#pragma unroll
        for (int u = 0; u < 16; ++u) buf[u] = __float2bfloat16(src[u]);
        *(uint4*)(As + s * 4096 + xr * 32 + xh)     = *(const uint4*)buf;
        *(uint4*)(As + s * 4096 + xr * 32 + xh + 8) = *(const uint4*)(buf + 8);
      }
      __syncthreads();
#pragma unroll
      for (int s = 0; s < 4; ++s)
        mfma_half<4, 2>(acc, As + s * 4096, Bs + s * 2048, wr, wc, q, ln);
    }
    // phase 2: h[idx] @ Whh^T, K = HS (loop_pre's leading barrier protects As)
    loop_pre(acc, h, idx, row0, Whh, HS, col0, HS, As, Bs);
#pragma unroll
    for (int j = 0; j < 2; ++j) {
      const int c = col0 + wc + j * 16 + ln;
      const float bj = b_ih[c] + b_hh[c];
#pragma unroll
      for (int i = 0; i < 4; ++i)
#pragma unroll
        for (int r = 0; r < 4; ++r) {
          const int rw = row0 + wr + i * 16 + q * 4 + r;
          hnewE[(size_t)rw * HS + c] = __float2bfloat16(fast_tanh(acc[i][j][r] + bj));
        }
    }
  }
}

// standalone loss (final step), 256 blocks.
__global__ __launch_bounds__(256) void k_loss(
    const bf16_t* __restrict__ tmpP, const bf16_t* __restrict__ Wp2,
    const float* __restrict__ bp2, const float* __restrict__ X,
    const float* __restrict__ Mm, float* __restrict__ accum)
{
  __shared__ bf16_t As[64 * 64], Bs[32 * 64];
  __shared__ float red[4];
  loss_tile(blockIdx.x, tmpP, Wp2, bp2, X, Mm, accum, As, Bs, red);
}

__global__ void k_cvt(const float* __restrict__ s, bf16_t* __restrict__ d, int n)
{
  const int i = blockIdx.x * 256 + threadIdx.x;
  if (i * 4 < n) {
    const float4 v = ((const float4*)s)[i];
    d[i * 4 + 0] = __float2bfloat16(v.x);
    d[i * 4 + 1] = __float2bfloat16(v.y);
    d[i * 4 + 2] = __float2bfloat16(v.z);
    d[i * 4 + 3] = __float2bfloat16(v.w);
  }
}

// fp32 [512][512] row-major -> frag-major bf16: chunk (c,r) at elems
// (c*512 + r)*8 holds W[r][c*8 .. c*8+8).  t = c*512 + r, coalesced stores.
__global__ void k_cvt_frag(const float* __restrict__ s, bf16_t* __restrict__ d)
{
  const int t = blockIdx.x * 256 + threadIdx.x;
  const int r = t & 511, c = t >> 9;
  const float4 v0 = *(const float4*)(s + (size_t)r * HS + c * 8);
  const float4 v1 = *(const float4*)(s + (size_t)r * HS + c * 8 + 4);
  __attribute__((aligned(16))) bf16_t buf[8];
  buf[0] = __float2bfloat16(v0.x); buf[1] = __float2bfloat16(v0.y);
  buf[2] = __float2bfloat16(v0.z); buf[3] = __float2bfloat16(v0.w);
  buf[4] = __float2bfloat16(v1.x); buf[5] = __float2bfloat16(v1.y);
  buf[6] = __float2bfloat16(v1.z); buf[7] = __float2bfloat16(v1.w);
  *(uint4*)(d + (size_t)t * 8) = *(const uint4*)buf;
}

__global__ void k_zero(float* __restrict__ p, size_t n4)
{
  size_t i = (size_t)blockIdx.x * blockDim.x + threadIdx.x;
  const size_t st = (size_t)gridDim.x * blockDim.x;
  const float4 z = {0.f, 0.f, 0.f, 0.f};
  for (; i < n4; i += st) ((float4*)p)[i] = z;
}

__global__ void k_zero_accum(float* accum)
{
  if (threadIdx.x < 2) accum[threadIdx.x] = 0.f;
}

__global__ void k_inv_clear(int* __restrict__ inv, int n)
{
  const int i = blockIdx.x * 256 + threadIdx.x;
  if (i < n) inv[i] = -1;
}

// inv[(k+1)*NS + bidx[k][e]] = e  for all k,e.  Row 0 stays all -1 (k=0).
__global__ void k_inv_build(const int* __restrict__ bidx, int* __restrict__ inv)
{
  const int i = blockIdx.x * 256 + threadIdx.x;   // [0, KOBS*ES)
  const int k = i >> 12, e = i & 4095;
  inv[(size_t)(k + 1) * NS + bidx[i]] = e;
}

__global__ void k_sum(const float* __restrict__ M, size_t n4, float* __restrict__ accum)
{
  __shared__ float red[256];
  float s = 0.f;
  for (size_t i = (size_t)blockIdx.x * blockDim.x + threadIdx.x; i < n4;
       i += (size_t)gridDim.x * blockDim.x) {
    const float4 v = ((const float4*)M)[i];
    s += v.x + v.y + v.z + v.w;
  }
  red[threadIdx.x] = s;
  __syncthreads();
  for (int st = 128; st > 0; st >>= 1) {
    if (threadIdx.x < st) red[threadIdx.x] += red[threadIdx.x + st];
    __syncthreads();
  }
  if (threadIdx.x == 0) atomicAdd(accum + 1, red[0]);
}

__global__ void k_final(const float* __restrict__ accum, float* __restrict__ out)
{
  out[0] = accum[0];
  out[1] = accum[0] / accum[1];
}

// ---------------------------------------------------------------------------
extern "C" void kernel_launch(void* const* d_in, const int* in_sizes, int n_in,
                              void* d_out, int out_size, void* d_ws, size_t ws_size,
                              hipStream_t stream)
{
  const float* X    = (const float*)d_in[0];
  const float* M    = (const float*)d_in[1];
  const int*   bidx = (const int*)d_in[2];
  const float* W_ih = (const float*)d_in[3];
  const float* b_ih = (const float*)d_in[4];
  const float* W_hh = (const float*)d_in[5];
  const float* b_hh = (const float*)d_in[6];
  const float* Wo1  = (const float*)d_in[7];
  const float* bo1  = (const float*)d_in[8];
  const float* Wo2  = (const float*)d_in[9];
  const float* bo2  = (const float*)d_in[10];
  const float* Wp1  = (const float*)d_in[11];
  const float* bp1  = (const float*)d_in[12];
  const float* Wp2  = (const float*)d_in[13];
  const float* bp2  = (const float*)d_in[14];
  float* out = (float*)d_out;

  char* w = (char*)d_ws;
  bf16_t* h     = (bf16_t*)w;                         w += (size_t)NS * HS * 2;
  bf16_t* tmpA  = (bf16_t*)w;                         w += (size_t)ES * HS * 2;
  bf16_t* tmpB  = (bf16_t*)w;                         w += (size_t)ES * HS * 2;
  bf16_t* hnewE = (bf16_t*)w;                         w += (size_t)ES * HS * 2;
  bf16_t* wWo1  = (bf16_t*)w;                         w += (size_t)HS * HS * 2;
  bf16_t* wWo2  = (bf16_t*)w;                         w += (size_t)HS * HS * 2;
  bf16_t* wWp1  = (bf16_t*)w;                         w += (size_t)HS * HS * 2;
  bf16_t* wWp2  = (bf16_t*)w;                         w += (size_t)DS * HS * 2;
  bf16_t* wWih  = (bf16_t*)w;                         w += (size_t)HS * DS * 2;
  bf16_t* wWhh  = (bf16_t*)w;                         w += (size_t)HS * HS * 2;
  int*    inv   = (int*)w;                            w += (size_t)(KOBS + 1) * NS * 4;
  float*  accum = (float*)w;

  k_zero<<<2048, 256, 0, stream>>>((float*)h, (size_t)NS * HS * 2 / 16);
  k_zero_accum<<<1, 64, 0, stream>>>(accum);
  k_inv_clear<<<(KOBS + 1) * NS / 256, 256, 0, stream>>>(inv, (KOBS + 1) * NS);
  k_inv_build<<<KOBS * ES / 256, 256, 0, stream>>>(bidx, inv);
  k_sum<<<2048, 256, 0, stream>>>(M, (size_t)KOBS * ES * DS / 4, accum);
  k_cvt_frag<<<128, 256, 0, stream>>>(Wo1, wWo1);   // frag-major for k_euler2
  k_cvt_frag<<<128, 256, 0, stream>>>(Wo2, wWo2);
  k_cvt<<<256, 256, 0, stream>>>(Wp1, wWp1, HS * HS);
  k_cvt<<<64, 256, 0, stream>>>(Wp2, wWp2, DS * HS);
  k_cvt<<<64, 256, 0, stream>>>(W_ih, wWih, HS * DS);
  k_cvt<<<256, 256, 0, stream>>>(W_hh, wWhh, HS * HS);

  const dim3 gObs(ES / 128, HS / 64, 3);   // z0 pre-relu, z1 rnn, z2 prev-loss

  for (int k = 0; k < KOBS; ++k) {
    const int*   idx = bidx + (size_t)k * ES;
    const float* Xk  = X + (size_t)k * ES * DS;
    bf16_t* tcur = (k & 1) ? tmpB : tmpA;
    const bf16_t* tprev = (k & 1) ? tmpA : tmpB;
    const float* Xp = k ? X + (size_t)(k - 1) * ES * DS : nullptr;
    const float* Mp = k ? M + (size_t)(k - 1) * ES * DS : nullptr;

    // both Euler steps fused; staging gathers prev RNN updates via inv.
    k_euler2<<<NS / 64, 512, 0, stream>>>(h, wWo1, bo1, wWo2, bo2,
                                          inv + (size_t)k * NS, hnewE);
    k_obs_fused<<<gObs, 256, 0, stream>>>(h, idx, wWp1, bp1, tcur,
                                          Xk, wWih, b_ih, wWhh, b_hh, hnewE,
                                          tprev, wWp2, bp2, Xp, Mp, accum);
  }
  // final step's loss (tmp of k=39 lives in tmpB since 39&1==1)
  k_loss<<<256, 256, 0, stream>>>(tmpB, wWp2, bp2,
                                  X + (size_t)(KOBS - 1) * ES * DS,
                                  M + (size_t)(KOBS - 1) * ES * DS, accum);

  k_final<<<1, 1, 0, stream>>>(accum, out);
}